// Round 6
// baseline (263.948 us; speedup 1.0000x reference)
//
#include <hip/hip_runtime.h>
#include <hip/hip_bf16.h>

#define NN 2000
#define NE 8192
#define DIM 10000
#define NCLS 10
#define HASH_SZ 32768
#define WORDS 313          // ceil(10000/32) packed sign words per node
#define ECH 8              // edge-chunk split for encpop grid.y

// ---- workspace layout (byte offsets) ----
#define WS_K       0                      // int        (distinct-edge counter)
#define WS_ENC     64                     // int[10016] per-dim xor-bit counts
#define WS_PAIRS   344576                 // u32[8192]  packed (rank[a]<<16)|rank[b] per distinct edge
#define WS_HASH    377344                 // int[32768] hash set
#define WS_PACK    508416                 // u32[313*2000] packed sign bits, layout [word][node]

#define ZERO_BYTES 40128                  // [0, 40128): K pad + ENC counts
#define ZERO_VEC  (ZERO_BYTES / 16)       // 2508 uint4 zero stores
#define HASH_VEC  (HASH_SZ * 4 / 16)      // 8192 uint4 0xFF stores
#define INIT_TOT  (ZERO_VEC + HASH_VEC)   // 10700
#define INIT_BLK  ((INIT_TOT + 255) / 256)        // 42
#define PACK_BLK  ((NN * WORDS + 255) / 256)      // 2446

// ---------- 1. fused init (replaces memsets) + sign-bit pack ----------
__global__ __launch_bounds__(256) void init_pack_kernel(const float* __restrict__ W,
                                                        char* __restrict__ ws) {
  if (blockIdx.x < INIT_BLK) {
    int t = blockIdx.x * 256 + threadIdx.x;
    if (t < ZERO_VEC) {
      reinterpret_cast<uint4*>(ws)[t] = make_uint4(0u, 0u, 0u, 0u);
    } else if (t < INIT_TOT) {
      reinterpret_cast<uint4*>(ws + WS_HASH)[t - ZERO_VEC] =
          make_uint4(0xFFFFFFFFu, 0xFFFFFFFFu, 0xFFFFFFFFu, 0xFFFFFFFFu);
    }
    return;
  }
  int t = (blockIdx.x - INIT_BLK) * 256 + threadIdx.x;
  if (t >= NN * WORDS) return;
  unsigned int* packed = (unsigned int*)(ws + WS_PACK);
  int w = t / NN;
  int node = t - w * NN;               // consecutive threads -> consecutive nodes, same word
  int d0 = w * 32;
  const float* p = W + (size_t)node * DIM + d0;   // 128B-aligned per-lane chunk
  unsigned int m = 0;
  if (d0 + 32 <= DIM) {
#pragma unroll
    for (int q = 0; q < 8; ++q) {
      float4 v4 = *reinterpret_cast<const float4*>(p + q * 4);
      m |= (__float_as_uint(v4.x) >> 31) << (q * 4);
      m |= (__float_as_uint(v4.y) >> 31) << (q * 4 + 1);
      m |= (__float_as_uint(v4.z) >> 31) << (q * 4 + 2);
      m |= (__float_as_uint(v4.w) >> 31) << (q * 4 + 3);
    }
  } else {
    for (int j = 0; j < DIM - d0; ++j) m |= (__float_as_uint(p[j]) >> 31) << j;
  }
  packed[(size_t)w * NN + node] = m;   // coalesced
}

// ---------- 2. mega: count + scan + stable CSR + pagerank + rank + dedup, one block ----------
__global__ __launch_bounds__(1024) void mega_kernel(const int* __restrict__ eidx,
                                                    char* __restrict__ ws) {
  __shared__ unsigned short s_ccol[NE];   // 16 KB  CSR col values
  __shared__ unsigned short s_ced[NE];    // 16 KB  edge ids during build; ranks after
  __shared__ int s_base[NN + 1];          // 8 KB   CSR row starts
  __shared__ int s_aux[2048];             // degc -> val (f32 alias)
  __shared__ int s_w[2048];               // rowcnt/scan -> fill cnt -> v (f32 alias)
  __shared__ float s_red[2][16];
  float* s_val = (float*)s_aux;
  float* s_v = (float*)s_w;
  unsigned short* s_rnk = s_ced;          // reuse after CSR consumers are done

  int tid = threadIdx.x;
  int wid = tid >> 6, lane = tid & 63;

  // --- zero counters ---
  for (int i = tid; i < 2048; i += 1024) { s_w[i] = 0; s_aux[i] = 0; }
  __syncthreads();

  // --- count: row counts (s_w) + col in-degree (s_aux) ---
  int er[8], ec[8];
#pragma unroll
  for (int k = 0; k < 8; ++k) {
    int e = tid + k * 1024;
    er[k] = eidx[e];
    ec[k] = eidx[NE + e];
    atomicAdd(&s_w[er[k]], 1);
    atomicAdd(&s_aux[ec[k]], 1);
  }
  __syncthreads();

  // --- inclusive scan of row counts -> base ---
  {
    int n0 = tid, n1 = tid + 1024;
    for (int st = 1; st < 2048; st <<= 1) {
      int v0 = (n0 >= st) ? s_w[n0 - st] : 0;
      int v1 = (n1 >= st) ? s_w[n1 - st] : 0;
      __syncthreads();
      s_w[n0] += v0;
      s_w[n1] += v1;
      __syncthreads();
    }
    if (tid == 0) s_base[0] = 0;
    for (int n = tid; n < NN; n += 1024) s_base[n + 1] = s_w[n];
  }
  __syncthreads();
  for (int i = tid; i < 2048; i += 1024) s_w[i] = 0;   // reuse as fill counters
  __syncthreads();

  // --- fill (atomic, unordered) keeping edge id ---
#pragma unroll
  for (int k = 0; k < 8; ++k) {
    int e = tid + k * 1024;
    int r = er[k];
    int slot = s_base[r] + atomicAdd(&s_w[r], 1);
    s_ccol[slot] = (unsigned short)ec[k];
    s_ced[slot] = (unsigned short)e;
  }
  __syncthreads();

  // --- per-node insertion sort by edge id -> exact edge order (stable CSR) ---
  for (int n = tid; n < NN; n += 1024) {
    int s0 = s_base[n], s1 = s_base[n + 1];
    for (int a = s0 + 1; a < s1; ++a) {
      unsigned short ke = s_ced[a], kc = s_ccol[a];
      int b = a - 1;
      while (b >= s0 && s_ced[b] > ke) {
        s_ced[b + 1] = s_ced[b];
        s_ccol[b + 1] = s_ccol[b];
        --b;
      }
      s_ced[b + 1] = ke;
      s_ccol[b + 1] = kc;
    }
  }
  // --- val[c] = 0.85f/degc[c], in place (elementwise) ---
  for (int n = tid; n < NN; n += 1024) {
    int d = s_aux[n];
    s_val[n] = 0.85f / (float)d;        // inf if deg==0: never referenced
  }
  // --- pagerank init (overwrites fill counters) ---
  const float p = 0.0005f;              // f32(1.0/2000)
  const float addv = 0.0005f * 0.15f;   // p * f32(1.0-0.85)
  for (int i = tid; i < NN; i += 1024) s_v[i] = p;
  __syncthreads();

  // --- pagerank power iteration (identical arithmetic to previous rounds) ---
  float err = __builtin_inff();
  int it = 0;
  int pb = 0;
  while (it < 100 && err >= 0.002f) {
    float vn0 = 0.f, vn1 = 0.f, ep = 0.f;
    {
      int n = tid;
      int s0 = s_base[n], e2 = s_base[n + 1];
      float sum = 0.f;
      for (int k = s0; k < e2; ++k) {
        int c = s_ccol[k];
        sum = __fadd_rn(sum, __fmul_rn(s_val[c], s_v[c]));
      }
      vn0 = __fadd_rn(sum, addv);
      ep += fabsf(__fsub_rn(vn0, s_v[n]));
    }
    if (tid + 1024 < NN) {
      int n = tid + 1024;
      int s0 = s_base[n], e2 = s_base[n + 1];
      float sum = 0.f;
      for (int k = s0; k < e2; ++k) {
        int c = s_ccol[k];
        sum = __fadd_rn(sum, __fmul_rn(s_val[c], s_v[c]));
      }
      vn1 = __fadd_rn(sum, addv);
      ep += fabsf(__fsub_rn(vn1, s_v[tid + 1024]));
    }
    for (int o = 32; o > 0; o >>= 1) ep += __shfl_down(ep, o, 64);
    if (lane == 0) s_red[pb][wid] = ep;
    __syncthreads();            // old s_v reads done; s_red[pb] visible
    s_v[tid] = vn0;
    if (tid + 1024 < NN) s_v[tid + 1024] = vn1;
    float t = 0.f;
#pragma unroll
    for (int w2 = 0; w2 < 16; ++w2) t += s_red[pb][w2];   // fixed order: bit-identical err
    err = t;
    pb ^= 1;
    ++it;
    __syncthreads();            // s_v writes visible for next iteration
  }

  // --- stable rank (integer count, ties by index) ---
  {
    int i0 = tid, i1 = tid + 1024;
    float vi0 = s_v[i0];
    float vi1 = (i1 < NN) ? s_v[i1] : 0.f;
    int r0 = 0, r1 = 0;
    for (int j = 0; j < NN; ++j) {
      float vj = s_v[j];                 // broadcast: conflict-free
      r0 += ((vj < vi0) || (vj == vi0 && j < i0)) ? 1 : 0;
      r1 += ((vj < vi1) || (vj == vi1 && j < i1)) ? 1 : 0;
    }
    s_rnk[i0] = (unsigned short)r0;      // overlays s_ced (dead)
    if (i1 < NN) s_rnk[i1] = (unsigned short)r1;
  }
  __syncthreads();

  // --- dedup undirected edges via global hash set; emit ranked pairs ---
  int* hash = (int*)(ws + WS_HASH);
  unsigned int* pairs = (unsigned int*)(ws + WS_PAIRS);
  int* Kp = (int*)(ws + WS_K);
#pragma unroll
  for (int k = 0; k < 8; ++k) {
    int r = er[k], c = ec[k];
    int a = min(r, c), b = max(r, c);
    int key = a * NN + b;
    unsigned int h = ((unsigned int)key * 2654435761u) >> 17;
    for (;;) {
      h &= (HASH_SZ - 1);
      int old = atomicCAS(&hash[h], -1, key);
      if (old == -1) {                   // this edge owns the distinct key
        int idx = atomicAdd(Kp, 1);
        pairs[idx] = ((unsigned int)s_rnk[a] << 16) | (unsigned int)s_rnk[b];
        break;
      }
      if (old == key) break;             // duplicate
      ++h;
    }
  }
}

// ---------- 3. per-dim xor-bit counts via ballot+popcount, edge-split grid ----------
__global__ __launch_bounds__(256) void encpop_kernel(char* __restrict__ ws) {
  const unsigned int* packed = (const unsigned int*)(ws + WS_PACK);
  const unsigned int* pairs = (const unsigned int*)(ws + WS_PAIRS);
  const int* Kp = (const int*)(ws + WS_K);
  int* enc_int = (int*)(ws + WS_ENC);
  __shared__ unsigned int s_col[NN];   // this word's bits for all 2000 rows (by rank)
  __shared__ int s_part[4][32];
  int w = blockIdx.x;
  int tid = threadIdx.x;
  int wid = tid >> 6, lane = tid & 63;
  for (int i = tid; i < NN; i += 256) s_col[i] = packed[(size_t)w * NN + i];
  __syncthreads();
  int K = *Kp;
  const int per = NE / ECH;            // 1024
  int e0 = blockIdx.y * per;
  int cnt[32];
#pragma unroll
  for (int b = 0; b < 32; ++b) cnt[b] = 0;
  for (int e = e0 + tid; e < e0 + per; e += 256) {   // uniform trip count: ballot-safe
    unsigned int x = 0;
    if (e < K) {
      unsigned int pk = pairs[e];
      x = s_col[pk >> 16] ^ s_col[pk & 0xffffu];
    }
#pragma unroll
    for (int b = 0; b < 32; ++b)
      cnt[b] += (int)__popcll(__ballot(x & (1u << b)));   // uniform per wave
  }
  if (lane == 0) {
#pragma unroll
    for (int b = 0; b < 32; ++b) s_part[wid][b] = cnt[b];
  }
  __syncthreads();
  if (tid < 32) {
    int tot = s_part[0][tid] + s_part[1][tid] + s_part[2][tid] + s_part[3][tid];
    if (tot) atomicAdd(&enc_int[w * 32 + tid], tot);   // exact integer accumulation
  }
}

// ---------- 4. out[c] = sum_d (K - 2*cnt[d]) * Wc[c][d] ----------
__global__ __launch_bounds__(256) void out_kernel(const float* __restrict__ Wc,
                                                  char* __restrict__ ws,
                                                  float* __restrict__ out) {
  const int* enc_int = (const int*)(ws + WS_ENC);
  int K = *(const int*)(ws + WS_K);
  __shared__ float red[4];
  int c = blockIdx.x;
  float s = 0.f;
  for (int d = threadIdx.x; d < DIM; d += 256)
    s += (float)(K - 2 * enc_int[d]) * Wc[c * DIM + d];
  for (int o = 32; o > 0; o >>= 1) s += __shfl_down(s, o, 64);
  if ((threadIdx.x & 63) == 0) red[threadIdx.x >> 6] = s;
  __syncthreads();
  if (threadIdx.x == 0) out[c] = red[0] + red[1] + red[2] + red[3];
}

extern "C" void kernel_launch(void* const* d_in, const int* in_sizes, int n_in,
                              void* d_out, int out_size, void* d_ws, size_t ws_size,
                              hipStream_t stream) {
  const int* eidx = (const int*)d_in[0];        // edge_index int32 [2, 8192]
  const float* Wn = (const float*)d_in[1];      // node_ids_weight f32 [2000, 10000]
  const float* Wc = (const float*)d_in[2];      // classify_weight f32 [10, 10000]
  float* out = (float*)d_out;
  char* ws = (char*)d_ws;

  init_pack_kernel<<<INIT_BLK + PACK_BLK, 256, 0, stream>>>(Wn, ws);
  mega_kernel<<<1, 1024, 0, stream>>>(eidx, ws);
  encpop_kernel<<<dim3(WORDS, ECH), 256, 0, stream>>>(ws);
  out_kernel<<<NCLS, 256, 0, stream>>>(Wc, ws, out);
}

// Round 7
// 111.859 us; speedup vs baseline: 2.3596x; 2.3596x over previous
//
#include <hip/hip_runtime.h>
#include <hip/hip_bf16.h>

#define NN 2000
#define NE 8192
#define DIM 10000
#define NCLS 10
#define NCHUNK 32          // edge chunks for stable CSR build
#define CPE 256            // edges per chunk
#define HASH_SZ 32768
#define WORDS 313          // ceil(10000/32) packed sign words per node
#define ECH 8              // edge-chunk split for encpop grid.y
#define RBLK 64            // i-rows per rank block

// ---- workspace layout (byte offsets) ----
#define WS_K       0                      // int        (distinct-edge counter)
#define WS_ENC     64                     // int[10016] per-dim xor-bit counts
#define WS_DEG     40128                  // int[2000]  (in-degree of col side)
#define WS_BASE    48128                  // int[2001]  (CSR row starts)
#define WS_CHUNK   56192                  // int[32*2000] per-chunk per-node counts -> offsets
#define WS_CCOL    312192                 // u16[8192]  CSR col values (edge-index order per node)
#define WS_V       328576                 // f32[2000]  pagerank result
#define WS_RANK    336576                 // int[2000]  stable rank of each node
#define WS_PAIRS   344576                 // u32[8192]  packed (rank[a]<<16)|rank[b] per distinct edge
#define WS_HASH    377344                 // int[32768] hash set
#define WS_PACK    508416                 // u32[313*2000] packed sign bits, layout [word][node]
#define WS_ZERO_BYTES 312192              // zero [0, WS_CCOL)

#define ZERO_VEC (WS_ZERO_BYTES / 16)     // 19512 uint4 zero stores
#define HASH_VEC (HASH_SZ * 4 / 16)       // 8192  uint4 0xFF stores
#define INIT_TOT (ZERO_VEC + HASH_VEC)    // 27704
#define INIT_BLK ((INIT_TOT + 255) / 256)         // 109
#define PACK_BLK ((NN * WORDS + 255) / 256)       // 2446

// ---------- 1. fused init (replaces memsets) + sign-bit pack ----------
__global__ __launch_bounds__(256) void init_pack_kernel(const float* __restrict__ W,
                                                        char* __restrict__ ws) {
  if (blockIdx.x < INIT_BLK) {
    int t = blockIdx.x * 256 + threadIdx.x;
    if (t < ZERO_VEC) {
      reinterpret_cast<uint4*>(ws)[t] = make_uint4(0u, 0u, 0u, 0u);
    } else if (t < INIT_TOT) {
      reinterpret_cast<uint4*>(ws + WS_HASH)[t - ZERO_VEC] =
          make_uint4(0xFFFFFFFFu, 0xFFFFFFFFu, 0xFFFFFFFFu, 0xFFFFFFFFu);
    }
    return;
  }
  int t = (blockIdx.x - INIT_BLK) * 256 + threadIdx.x;
  if (t >= NN * WORDS) return;
  unsigned int* packed = (unsigned int*)(ws + WS_PACK);
  int w = t / NN;
  int node = t - w * NN;               // consecutive threads -> consecutive nodes, same word
  int d0 = w * 32;
  const float* p = W + (size_t)node * DIM + d0;   // 128B-aligned per-lane chunk
  unsigned int m = 0;
  if (d0 + 32 <= DIM) {
#pragma unroll
    for (int q = 0; q < 8; ++q) {
      float4 v4 = *reinterpret_cast<const float4*>(p + q * 4);
      m |= (__float_as_uint(v4.x) >> 31) << (q * 4);
      m |= (__float_as_uint(v4.y) >> 31) << (q * 4 + 1);
      m |= (__float_as_uint(v4.z) >> 31) << (q * 4 + 2);
      m |= (__float_as_uint(v4.w) >> 31) << (q * 4 + 3);
    }
  } else {
    for (int j = 0; j < DIM - d0; ++j) m |= (__float_as_uint(p[j]) >> 31) << j;
  }
  packed[(size_t)w * NN + node] = m;   // coalesced
}

// ---------- 2. counts: deg (col side) + per-chunk per-node row counts ----------
__global__ __launch_bounds__(256) void count_kernel(const int* __restrict__ eidx,
                                                    int* __restrict__ deg,
                                                    int* __restrict__ chunk) {
  int e = blockIdx.x * CPE + threadIdx.x;
  int r = eidx[e];
  int c = eidx[NE + e];
  atomicAdd(&deg[c], 1);
  atomicAdd(&chunk[blockIdx.x * NN + r], 1);
}

// ---------- 3. scan: node totals -> exclusive base; chunk counts -> chunk offsets ----------
__global__ __launch_bounds__(1024) void scan_kernel(int* __restrict__ base,
                                                    int* __restrict__ chunk) {
  __shared__ int s[2048];
  int tid = threadIdx.x;
  int n0 = tid, n1 = tid + 1024;
  int t0 = 0, t1 = 0;
  for (int b = 0; b < NCHUNK; ++b) t0 += chunk[b * NN + n0];
  if (n1 < NN) for (int b = 0; b < NCHUNK; ++b) t1 += chunk[b * NN + n1];
  s[n0] = t0;
  s[n1] = (n1 < NN) ? t1 : 0;
  __syncthreads();
  for (int dstep = 1; dstep < 2048; dstep <<= 1) {
    int v0 = (n0 >= dstep) ? s[n0 - dstep] : 0;
    int v1 = (n1 >= dstep) ? s[n1 - dstep] : 0;
    __syncthreads();
    s[n0] += v0;
    s[n1] += v1;
    __syncthreads();
  }
  if (tid == 0) base[0] = 0;
  for (int n = tid; n < NN; n += 1024) base[n + 1] = s[n];
  // in-place turn chunk counts into chunk start offsets (stable: chunk-major = edge order)
  for (int n = tid; n < NN; n += 1024) {
    int run = (n == 0) ? 0 : s[n - 1];
    for (int b = 0; b < NCHUNK; ++b) {
      int t = chunk[b * NN + n];
      chunk[b * NN + n] = run;
      run += t;
    }
  }
}

// ---------- 4. stable fill: CSR col list in edge-index order per node ----------
__global__ __launch_bounds__(256) void fill_kernel(const int* __restrict__ eidx,
                                                   const int* __restrict__ chunk,
                                                   unsigned short* __restrict__ ccol) {
  __shared__ int s_rows[CPE];
  int tid = threadIdx.x;
  int e = blockIdx.x * CPE + tid;
  int r = eidx[e];
  int c = eidx[NE + e];
  s_rows[tid] = r;
  __syncthreads();
  int cntb = 0;
  for (int j = 0; j < tid; ++j) cntb += (s_rows[j] == r) ? 1 : 0;
  int slot = chunk[blockIdx.x * NN + r] + cntb;
  ccol[slot] = (unsigned short)c;
}

// ---------- 5. pagerank: single block, 1 barrier/iter, wv double-buffer, v in regs ----------
// Bit-exactness: wv[c] = fmul_rn(val[c], v_prev[c]) is the same f32 product the old code
// computed inside the gather; adds stay in CSR edge order; err reduction order unchanged.
__global__ __launch_bounds__(1024) void pr_kernel(char* __restrict__ ws) {
  const int* deg_g = (const int*)(ws + WS_DEG);
  const int* base_g = (const int*)(ws + WS_BASE);
  const unsigned short* ccol_g = (const unsigned short*)(ws + WS_CCOL);
  float* vout = (float*)(ws + WS_V);

  __shared__ unsigned short s_ccol[NE];   // 16384 B
  __shared__ float s_val[NN];             // 8000 B: 0.85f/deg[c]
  __shared__ float s_wv[2][2048];         // 16384 B: double-buffered val[c]*v[c]
  __shared__ int s_base[NN + 1];          // 8004 B
  __shared__ float s_red[2][16];

  int tid = threadIdx.x;
  int wid = tid >> 6, lane = tid & 63;
  for (int i = tid; i < NE; i += 1024) s_ccol[i] = ccol_g[i];
  for (int i = tid; i < NN; i += 1024) s_val[i] = 0.85f / (float)deg_g[i]; // inf if deg==0: never gathered
  for (int i = tid; i <= NN; i += 1024) s_base[i] = base_g[i];
  const float p = 0.0005f;                 // f32(1.0/2000)
  const float addv = 0.0005f * 0.15f;      // p * f32(1.0-0.85)
  float vc0 = p, vc1 = p;                  // own v values live in registers
  // s_val[tid], s_val[tid+1024] were written by THIS thread -> no barrier needed yet
  s_wv[0][tid] = __fmul_rn(s_val[tid], p);
  if (tid + 1024 < NN) s_wv[0][tid + 1024] = __fmul_rn(s_val[tid + 1024], p);
  __syncthreads();
  int b0s = s_base[tid], b0e = s_base[tid + 1];
  int b1s = 0, b1e = 0;
  if (tid + 1024 < NN) { b1s = s_base[tid + 1024]; b1e = s_base[tid + 1025]; }

  float err = __builtin_inff();
  int it = 0;
  int pb = 0;
  while (it < 100 && err >= 0.002f) {
    const float* wv = s_wv[pb];
    float ep = 0.f;
    float sum = 0.f;
    for (int k = b0s; k < b0e; ++k) sum = __fadd_rn(sum, wv[s_ccol[k]]);
    float vn0 = __fadd_rn(sum, addv);
    ep += fabsf(__fsub_rn(vn0, vc0));
    float vn1 = vc1;
    if (tid + 1024 < NN) {
      sum = 0.f;
      for (int k = b1s; k < b1e; ++k) sum = __fadd_rn(sum, wv[s_ccol[k]]);
      vn1 = __fadd_rn(sum, addv);
      ep += fabsf(__fsub_rn(vn1, vc1));
    }
    float* wvn = s_wv[pb ^ 1];             // safe: other threads gather from s_wv[pb]
    wvn[tid] = __fmul_rn(s_val[tid], vn0);
    if (tid + 1024 < NN) wvn[tid + 1024] = __fmul_rn(s_val[tid + 1024], vn1);
    vc0 = vn0; vc1 = vn1;
    for (int o = 32; o > 0; o >>= 1) ep += __shfl_down(ep, o, 64);
    if (lane == 0) s_red[pb][wid] = ep;
    __syncthreads();            // wv[pb^1] + s_red[pb] visible; all wv[pb] reads done
    float t = 0.f;
#pragma unroll
    for (int w2 = 0; w2 < 16; ++w2) t += s_red[pb][w2];   // fixed order: bit-identical err
    err = t;
    pb ^= 1;
    ++it;
  }
  vout[tid] = vc0;
  if (tid + 1024 < NN) vout[tid + 1024] = vc1;
}

// ---------- 6. stable rank: LDS-staged, 4-way j-split, 32 blocks ----------
__global__ __launch_bounds__(256) void rank_kernel(char* __restrict__ ws) {
  const float* v = (const float*)(ws + WS_V);
  int* rnk = (int*)(ws + WS_RANK);
  __shared__ float s_v[NN];
  __shared__ int s_part[4][RBLK];
  int tid = threadIdx.x;
  for (int j = tid; j < NN; j += 256) s_v[j] = v[j];
  __syncthreads();
  int li = tid & (RBLK - 1);
  int seg = tid >> 6;                    // 0..3
  int i = blockIdx.x * RBLK + li;
  float vi = (i < NN) ? s_v[i] : 0.f;
  const int jper = NN / 4;               // 500
  int j0 = seg * jper, j1 = j0 + jper;
  int r = 0;
  for (int j = j0; j < j1; ++j) {
    float vj = s_v[j];                   // broadcast: conflict-free
    r += ((vj < vi) || (vj == vi && j < i)) ? 1 : 0;
  }
  s_part[seg][li] = r;
  __syncthreads();
  if (tid < RBLK) {
    int i2 = blockIdx.x * RBLK + tid;
    if (i2 < NN)
      rnk[i2] = s_part[0][tid] + s_part[1][tid] + s_part[2][tid] + s_part[3][tid];
  }
}

// ---------- 7. dedup undirected edges via hash set; emit packed ranked pairs ----------
__global__ __launch_bounds__(256) void dedup_kernel(const int* __restrict__ eidx,
                                                    char* __restrict__ ws) {
  int* hash = (int*)(ws + WS_HASH);
  unsigned int* pairs = (unsigned int*)(ws + WS_PAIRS);
  int* Kp = (int*)(ws + WS_K);
  const int* rnk = (const int*)(ws + WS_RANK);
  int e = blockIdx.x * 256 + threadIdx.x;
  int r = eidx[e], c = eidx[NE + e];
  int a = min(r, c), b = max(r, c);
  int key = a * NN + b;
  unsigned int h = ((unsigned int)key * 2654435761u) >> 17;
  for (;;) {
    h &= (HASH_SZ - 1);
    int old = atomicCAS(&hash[h], -1, key);
    if (old == -1) {                       // this edge owns the distinct key
      int idx = atomicAdd(Kp, 1);
      pairs[idx] = ((unsigned int)rnk[a] << 16) | (unsigned int)rnk[b];
      return;
    }
    if (old == key) return;                // duplicate
    ++h;
  }
}

// ---------- 8. per-dim xor-bit counts via ballot+popcount, edge-split grid ----------
__global__ __launch_bounds__(256) void encpop_kernel(char* __restrict__ ws) {
  const unsigned int* packed = (const unsigned int*)(ws + WS_PACK);
  const unsigned int* pairs = (const unsigned int*)(ws + WS_PAIRS);
  const int* Kp = (const int*)(ws + WS_K);
  int* enc_int = (int*)(ws + WS_ENC);
  __shared__ unsigned int s_col[NN];   // this word's bits for all 2000 rows (by rank)
  __shared__ int s_part[4][32];
  int w = blockIdx.x;
  int tid = threadIdx.x;
  int wid = tid >> 6, lane = tid & 63;
  for (int i = tid; i < NN; i += 256) s_col[i] = packed[(size_t)w * NN + i];
  __syncthreads();
  int K = *Kp;
  const int per = NE / ECH;            // 1024
  int e0 = blockIdx.y * per;
  int cnt[32];
#pragma unroll
  for (int b = 0; b < 32; ++b) cnt[b] = 0;
  for (int e = e0 + tid; e < e0 + per; e += 256) {   // uniform trip count: ballot-safe
    unsigned int x = 0;
    if (e < K) {
      unsigned int pk = pairs[e];
      x = s_col[pk >> 16] ^ s_col[pk & 0xffffu];
    }
#pragma unroll
    for (int b = 0; b < 32; ++b)
      cnt[b] += (int)__popcll(__ballot(x & (1u << b)));   // uniform per wave
  }
  if (lane == 0) {
#pragma unroll
    for (int b = 0; b < 32; ++b) s_part[wid][b] = cnt[b];
  }
  __syncthreads();
  if (tid < 32) {
    int tot = s_part[0][tid] + s_part[1][tid] + s_part[2][tid] + s_part[3][tid];
    if (tot) atomicAdd(&enc_int[w * 32 + tid], tot);   // exact integer accumulation
  }
}

// ---------- 9. out[c] = sum_d (K - 2*cnt[d]) * Wc[c][d] ----------
__global__ __launch_bounds__(256) void out_kernel(const float* __restrict__ Wc,
                                                  char* __restrict__ ws,
                                                  float* __restrict__ out) {
  const int* enc_int = (const int*)(ws + WS_ENC);
  int K = *(const int*)(ws + WS_K);
  __shared__ float red[4];
  int c = blockIdx.x;
  float s = 0.f;
  for (int d = threadIdx.x; d < DIM; d += 256)
    s += (float)(K - 2 * enc_int[d]) * Wc[c * DIM + d];
  for (int o = 32; o > 0; o >>= 1) s += __shfl_down(s, o, 64);
  if ((threadIdx.x & 63) == 0) red[threadIdx.x >> 6] = s;
  __syncthreads();
  if (threadIdx.x == 0) out[c] = red[0] + red[1] + red[2] + red[3];
}

extern "C" void kernel_launch(void* const* d_in, const int* in_sizes, int n_in,
                              void* d_out, int out_size, void* d_ws, size_t ws_size,
                              hipStream_t stream) {
  const int* eidx = (const int*)d_in[0];        // edge_index int32 [2, 8192]
  const float* Wn = (const float*)d_in[1];      // node_ids_weight f32 [2000, 10000]
  const float* Wc = (const float*)d_in[2];      // classify_weight f32 [10, 10000]
  float* out = (float*)d_out;
  char* ws = (char*)d_ws;

  init_pack_kernel<<<INIT_BLK + PACK_BLK, 256, 0, stream>>>(Wn, ws);

  count_kernel<<<NCHUNK, CPE, 0, stream>>>(eidx, (int*)(ws + WS_DEG), (int*)(ws + WS_CHUNK));
  scan_kernel<<<1, 1024, 0, stream>>>((int*)(ws + WS_BASE), (int*)(ws + WS_CHUNK));
  fill_kernel<<<NCHUNK, CPE, 0, stream>>>(eidx, (const int*)(ws + WS_CHUNK),
                                          (unsigned short*)(ws + WS_CCOL));
  pr_kernel<<<1, 1024, 0, stream>>>(ws);
  rank_kernel<<<(NN + RBLK - 1) / RBLK, 256, 0, stream>>>(ws);
  dedup_kernel<<<NE / 256, 256, 0, stream>>>(eidx, ws);
  encpop_kernel<<<dim3(WORDS, ECH), 256, 0, stream>>>(ws);
  out_kernel<<<NCLS, 256, 0, stream>>>(Wc, ws, out);
}

// Round 8
// 105.589 us; speedup vs baseline: 2.4998x; 1.0594x over previous
//
#include <hip/hip_runtime.h>
#include <hip/hip_bf16.h>

#define NN 2000
#define NE 8192
#define DIM 10000
#define NCLS 10
#define HASH_SZ 32768
#define WORDS 313          // ceil(10000/32) packed sign words per node
#define ECH 8              // edge-chunk split for encpop grid.y
#define RBLK 64            // i-rows per rank block

// ---- workspace layout (byte offsets) ----
#define WS_K       0                      // int        (distinct-edge counter)
#define WS_ENC     64                     // int[10016] per-dim xor-bit counts
#define WS_V       328576                 // f32[2000]  pagerank result
#define WS_RANK    336576                 // int[2000]  stable rank of each node
#define WS_PAIRS   344576                 // u32[8192]  packed (rank[a]<<16)|rank[b] per distinct edge
#define WS_HASH    377344                 // int[32768] hash set
#define WS_PACK    508416                 // u32[313*2000] packed sign bits, layout [word][node]

#define ZERO_BYTES 40128                  // [0, 40128): K + ENC counts
#define ZERO_VEC  (ZERO_BYTES / 16)       // 2508 uint4 zero stores
#define HASH_VEC  (HASH_SZ * 4 / 16)      // 8192 uint4 0xFF stores
#define INIT_TOT  (ZERO_VEC + HASH_VEC)   // 10700
#define INIT_BLK  ((INIT_TOT + 255) / 256)        // 42
#define PACK_BLK  ((NN * WORDS + 255) / 256)      // 2446

// ---------- 1. fused init (replaces memsets) + sign-bit pack ----------
__global__ __launch_bounds__(256) void init_pack_kernel(const float* __restrict__ W,
                                                        char* __restrict__ ws) {
  if (blockIdx.x < INIT_BLK) {
    int t = blockIdx.x * 256 + threadIdx.x;
    if (t < ZERO_VEC) {
      reinterpret_cast<uint4*>(ws)[t] = make_uint4(0u, 0u, 0u, 0u);
    } else if (t < INIT_TOT) {
      reinterpret_cast<uint4*>(ws + WS_HASH)[t - ZERO_VEC] =
          make_uint4(0xFFFFFFFFu, 0xFFFFFFFFu, 0xFFFFFFFFu, 0xFFFFFFFFu);
    }
    return;
  }
  int t = (blockIdx.x - INIT_BLK) * 256 + threadIdx.x;
  if (t >= NN * WORDS) return;
  unsigned int* packed = (unsigned int*)(ws + WS_PACK);
  int w = t / NN;
  int node = t - w * NN;               // consecutive threads -> consecutive nodes, same word
  int d0 = w * 32;
  const float* p = W + (size_t)node * DIM + d0;   // 128B-aligned per-lane chunk
  unsigned int m = 0;
  if (d0 + 32 <= DIM) {
#pragma unroll
    for (int q = 0; q < 8; ++q) {
      float4 v4 = *reinterpret_cast<const float4*>(p + q * 4);
      m |= (__float_as_uint(v4.x) >> 31) << (q * 4);
      m |= (__float_as_uint(v4.y) >> 31) << (q * 4 + 1);
      m |= (__float_as_uint(v4.z) >> 31) << (q * 4 + 2);
      m |= (__float_as_uint(v4.w) >> 31) << (q * 4 + 3);
    }
  } else {
    for (int j = 0; j < DIM - d0; ++j) m |= (__float_as_uint(p[j]) >> 31) << j;
  }
  packed[(size_t)w * NN + node] = m;   // coalesced
}

// DPP wave64 sum: canonical gfx9 sequence; lane 63 ends with the full wave sum.
// Order of adds differs from shfl butterfly — only used for the err gate, which
// has ~5 orders of magnitude of tolerance at the 0.002 crossing.
__device__ __forceinline__ float wave_sum_dpp(float x) {
#define DPPADD(ctrl, rm, bm)                                                     \
  {                                                                              \
    int y_ = __builtin_amdgcn_update_dpp(0, __float_as_int(x), ctrl, rm, bm, false); \
    x = __fadd_rn(x, __int_as_float(y_));                                        \
  }
  DPPADD(0x111, 0xF, 0xF);  // row_shr:1
  DPPADD(0x112, 0xF, 0xF);  // row_shr:2
  DPPADD(0x114, 0xF, 0xE);  // row_shr:4
  DPPADD(0x118, 0xF, 0xC);  // row_shr:8
  DPPADD(0x142, 0xA, 0xF);  // row_bcast:15 -> rows 1,3
  DPPADD(0x143, 0xC, 0xF);  // row_bcast:31 -> rows 2,3
#undef DPPADD
  return x;                  // valid in lane 63
}

// ---------- 2. build (count+scan+stable CSR) + pagerank, one block ----------
// CSR construction identical to R6's verified build (atomic fill + per-node
// insertion sort by edge id == edge-index order). PR gather arithmetic is the
// R7 1-barrier wv-double-buffer form (bit-exact f32, CSR edge order).
__global__ __launch_bounds__(1024) void build_pr_kernel(const int* __restrict__ eidx,
                                                        char* __restrict__ ws) {
  __shared__ unsigned short s_ccol[NE];   // 16 KB  CSR col values
  __shared__ unsigned short s_ced[NE];    // 16 KB  edge ids during build
  __shared__ int s_base[NN + 1];          // 8 KB   CSR row starts
  __shared__ int s_aux[2048];             // degc -> val (f32 alias, in-place)
  __shared__ int s_w[2048];               // rowcnt/scan -> fill counters
  __shared__ float s_wv[2][2048];         // 16 KB  double-buffered val[c]*v[c]
  __shared__ float s_red[2][16];
  float* s_val = (float*)s_aux;

  int tid = threadIdx.x;
  int wid = tid >> 6, lane = tid & 63;

  for (int i = tid; i < 2048; i += 1024) { s_w[i] = 0; s_aux[i] = 0; }
  __syncthreads();

  // --- count: row counts (s_w) + col in-degree (s_aux) ---
  int er[8], ec[8];
#pragma unroll
  for (int k = 0; k < 8; ++k) {
    int e = tid + k * 1024;
    er[k] = eidx[e];
    ec[k] = eidx[NE + e];
    atomicAdd(&s_w[er[k]], 1);
    atomicAdd(&s_aux[ec[k]], 1);
  }
  __syncthreads();

  // --- inclusive scan of row counts -> base ---
  {
    int n0 = tid, n1 = tid + 1024;
    for (int st = 1; st < 2048; st <<= 1) {
      int v0 = (n0 >= st) ? s_w[n0 - st] : 0;
      int v1 = (n1 >= st) ? s_w[n1 - st] : 0;
      __syncthreads();
      s_w[n0] += v0;
      s_w[n1] += v1;
      __syncthreads();
    }
    if (tid == 0) s_base[0] = 0;
    for (int n = tid; n < NN; n += 1024) s_base[n + 1] = s_w[n];
  }
  __syncthreads();
  for (int i = tid; i < 2048; i += 1024) s_w[i] = 0;   // reuse as fill counters
  __syncthreads();

  // --- fill (atomic, unordered) keeping edge id ---
#pragma unroll
  for (int k = 0; k < 8; ++k) {
    int e = tid + k * 1024;
    int r = er[k];
    int slot = s_base[r] + atomicAdd(&s_w[r], 1);
    s_ccol[slot] = (unsigned short)ec[k];
    s_ced[slot] = (unsigned short)e;
  }
  __syncthreads();

  // --- per-node insertion sort by edge id (stable CSR) + val + wv[0] init ---
  const float p = 0.0005f;              // f32(1.0/2000)
  const float addv = 0.0005f * 0.15f;   // p * f32(1.0-0.85)
  for (int n = tid; n < NN; n += 1024) {
    int s0 = s_base[n], s1 = s_base[n + 1];
    for (int a = s0 + 1; a < s1; ++a) {
      unsigned short ke = s_ced[a], kc = s_ccol[a];
      int b = a - 1;
      while (b >= s0 && s_ced[b] > ke) {
        s_ced[b + 1] = s_ced[b];
        s_ccol[b + 1] = s_ccol[b];
        --b;
      }
      s_ced[b + 1] = ke;
      s_ccol[b + 1] = kc;
    }
    float vv = 0.85f / (float)s_aux[n];   // inf if deg==0: never gathered
    s_val[n] = vv;                        // in-place alias of s_aux[n]
    s_wv[0][n] = __fmul_rn(vv, p);
  }
  __syncthreads();

  int b0s = s_base[tid], b0e = s_base[tid + 1];
  int b1s = 0, b1e = 0;
  if (tid + 1024 < NN) { b1s = s_base[tid + 1024]; b1e = s_base[tid + 1025]; }
  float vc0 = p, vc1 = p;

  float err = __builtin_inff();
  int it = 0;
  int pb = 0;
  while (it < 100 && err >= 0.002f) {
    const float* wv = s_wv[pb];
    float ep = 0.f;
    float sum = 0.f;
    for (int k = b0s; k < b0e; ++k) sum = __fadd_rn(sum, wv[s_ccol[k]]);
    float vn0 = __fadd_rn(sum, addv);
    ep += fabsf(__fsub_rn(vn0, vc0));
    float vn1 = vc1;
    if (tid + 1024 < NN) {
      sum = 0.f;
      for (int k = b1s; k < b1e; ++k) sum = __fadd_rn(sum, wv[s_ccol[k]]);
      vn1 = __fadd_rn(sum, addv);
      ep += fabsf(__fsub_rn(vn1, vc1));
    }
    float* wvn = s_wv[pb ^ 1];             // safe: gathers read s_wv[pb]
    wvn[tid] = __fmul_rn(s_val[tid], vn0);
    if (tid + 1024 < NN) wvn[tid + 1024] = __fmul_rn(s_val[tid + 1024], vn1);
    vc0 = vn0; vc1 = vn1;
    float wsum = wave_sum_dpp(ep);         // ~50 cyc VALU vs ~720 cyc shfl chain
    if (lane == 63) s_red[pb][wid] = wsum;
    __syncthreads();            // wv[pb^1] + s_red[pb] visible; wv[pb] reads done
    float t = 0.f;
#pragma unroll
    for (int w2 = 0; w2 < 16; ++w2) t += s_red[pb][w2];   // fixed order
    err = t;
    pb ^= 1;
    ++it;
  }
  float* vout = (float*)(ws + WS_V);
  vout[tid] = vc0;
  if (tid + 1024 < NN) vout[tid + 1024] = vc1;
}

// ---------- 3. stable rank: LDS-staged, 4-way j-split, 32 blocks ----------
__global__ __launch_bounds__(256) void rank_kernel(char* __restrict__ ws) {
  const float* v = (const float*)(ws + WS_V);
  int* rnk = (int*)(ws + WS_RANK);
  __shared__ float s_v[NN];
  __shared__ int s_part[4][RBLK];
  int tid = threadIdx.x;
  for (int j = tid; j < NN; j += 256) s_v[j] = v[j];
  __syncthreads();
  int li = tid & (RBLK - 1);
  int seg = tid >> 6;                    // 0..3
  int i = blockIdx.x * RBLK + li;
  float vi = (i < NN) ? s_v[i] : 0.f;
  const int jper = NN / 4;               // 500
  int j0 = seg * jper, j1 = j0 + jper;
  int r = 0;
  for (int j = j0; j < j1; ++j) {
    float vj = s_v[j];                   // broadcast: conflict-free
    r += ((vj < vi) || (vj == vi && j < i)) ? 1 : 0;
  }
  s_part[seg][li] = r;
  __syncthreads();
  if (tid < RBLK) {
    int i2 = blockIdx.x * RBLK + tid;
    if (i2 < NN)
      rnk[i2] = s_part[0][tid] + s_part[1][tid] + s_part[2][tid] + s_part[3][tid];
  }
}

// ---------- 4. dedup undirected edges via hash set; emit packed ranked pairs ----------
__global__ __launch_bounds__(256) void dedup_kernel(const int* __restrict__ eidx,
                                                    char* __restrict__ ws) {
  int* hash = (int*)(ws + WS_HASH);
  unsigned int* pairs = (unsigned int*)(ws + WS_PAIRS);
  int* Kp = (int*)(ws + WS_K);
  const int* rnk = (const int*)(ws + WS_RANK);
  int e = blockIdx.x * 256 + threadIdx.x;
  int r = eidx[e], c = eidx[NE + e];
  int a = min(r, c), b = max(r, c);
  int key = a * NN + b;
  unsigned int h = ((unsigned int)key * 2654435761u) >> 17;
  for (;;) {
    h &= (HASH_SZ - 1);
    int old = atomicCAS(&hash[h], -1, key);
    if (old == -1) {                       // this edge owns the distinct key
      int idx = atomicAdd(Kp, 1);
      pairs[idx] = ((unsigned int)rnk[a] << 16) | (unsigned int)rnk[b];
      return;
    }
    if (old == key) return;                // duplicate
    ++h;
  }
}

// ---------- 5. per-dim xor-bit counts via ballot+popcount, edge-split grid ----------
__global__ __launch_bounds__(256) void encpop_kernel(char* __restrict__ ws) {
  const unsigned int* packed = (const unsigned int*)(ws + WS_PACK);
  const unsigned int* pairs = (const unsigned int*)(ws + WS_PAIRS);
  const int* Kp = (const int*)(ws + WS_K);
  int* enc_int = (int*)(ws + WS_ENC);
  __shared__ unsigned int s_col[NN];   // this word's bits for all 2000 rows (by rank)
  __shared__ int s_part[4][32];
  int w = blockIdx.x;
  int tid = threadIdx.x;
  int wid = tid >> 6, lane = tid & 63;
  for (int i = tid; i < NN; i += 256) s_col[i] = packed[(size_t)w * NN + i];
  __syncthreads();
  int K = *Kp;
  const int per = NE / ECH;            // 1024
  int e0 = blockIdx.y * per;
  int cnt[32];
#pragma unroll
  for (int b = 0; b < 32; ++b) cnt[b] = 0;
  for (int e = e0 + tid; e < e0 + per; e += 256) {   // uniform trip count: ballot-safe
    unsigned int x = 0;
    if (e < K) {
      unsigned int pk = pairs[e];
      x = s_col[pk >> 16] ^ s_col[pk & 0xffffu];
    }
#pragma unroll
    for (int b = 0; b < 32; ++b)
      cnt[b] += (int)__popcll(__ballot(x & (1u << b)));   // uniform per wave
  }
  if (lane == 0) {
#pragma unroll
    for (int b = 0; b < 32; ++b) s_part[wid][b] = cnt[b];
  }
  __syncthreads();
  if (tid < 32) {
    int tot = s_part[0][tid] + s_part[1][tid] + s_part[2][tid] + s_part[3][tid];
    if (tot) atomicAdd(&enc_int[w * 32 + tid], tot);   // exact integer accumulation
  }
}

// ---------- 6. out[c] = sum_d (K - 2*cnt[d]) * Wc[c][d] ----------
__global__ __launch_bounds__(256) void out_kernel(const float* __restrict__ Wc,
                                                  char* __restrict__ ws,
                                                  float* __restrict__ out) {
  const int* enc_int = (const int*)(ws + WS_ENC);
  int K = *(const int*)(ws + WS_K);
  __shared__ float red[4];
  int c = blockIdx.x;
  float s = 0.f;
  for (int d = threadIdx.x; d < DIM; d += 256)
    s += (float)(K - 2 * enc_int[d]) * Wc[c * DIM + d];
  for (int o = 32; o > 0; o >>= 1) s += __shfl_down(s, o, 64);
  if ((threadIdx.x & 63) == 0) red[threadIdx.x >> 6] = s;
  __syncthreads();
  if (threadIdx.x == 0) out[c] = red[0] + red[1] + red[2] + red[3];
}

extern "C" void kernel_launch(void* const* d_in, const int* in_sizes, int n_in,
                              void* d_out, int out_size, void* d_ws, size_t ws_size,
                              hipStream_t stream) {
  const int* eidx = (const int*)d_in[0];        // edge_index int32 [2, 8192]
  const float* Wn = (const float*)d_in[1];      // node_ids_weight f32 [2000, 10000]
  const float* Wc = (const float*)d_in[2];      // classify_weight f32 [10, 10000]
  float* out = (float*)d_out;
  char* ws = (char*)d_ws;

  init_pack_kernel<<<INIT_BLK + PACK_BLK, 256, 0, stream>>>(Wn, ws);
  build_pr_kernel<<<1, 1024, 0, stream>>>(eidx, ws);
  rank_kernel<<<(NN + RBLK - 1) / RBLK, 256, 0, stream>>>(ws);
  dedup_kernel<<<NE / 256, 256, 0, stream>>>(eidx, ws);
  encpop_kernel<<<dim3(WORDS, ECH), 256, 0, stream>>>(ws);
  out_kernel<<<NCLS, 256, 0, stream>>>(Wc, ws, out);
}

// Round 9
// 96.051 us; speedup vs baseline: 2.7480x; 1.0993x over previous
//
#include <hip/hip_runtime.h>
#include <hip/hip_bf16.h>

#define NN 2000
#define NE 8192
#define DIM 10000
#define NCLS 10
#define HASH_SZ 32768
#define WORDS 313          // ceil(10000/32) packed sign words per node
#define ECH 8              // edge-chunk split for encpop grid.y
#define RBLK 64            // i-rows per rank block
#define REGD 12            // register-hoisted CSR entries per node (fallback loop beyond)
#define DUMMY 2047         // wv[DUMMY] == +0.0f always

// ---- workspace layout (byte offsets) ----
#define WS_K       0                      // int        (distinct-edge counter)
#define WS_ENC     64                     // int[10016] per-dim xor-bit counts
#define WS_V       328576                 // f32[2000]  pagerank result
#define WS_RANK    336576                 // int[2000]  stable rank of each node
#define WS_PAIRS   344576                 // u32[8192]  packed (rank[a]<<16)|rank[b] per distinct edge
#define WS_HASH    377344                 // int[32768] hash set
#define WS_PACK    508416                 // u32[313*2000] packed sign bits, layout [word][node]

#define ZERO_BYTES 40128                  // [0, 40128): K + ENC counts
#define ZERO_VEC  (ZERO_BYTES / 16)       // 2508 uint4 zero stores
#define HASH_VEC  (HASH_SZ * 4 / 16)      // 8192 uint4 0xFF stores
#define INIT_TOT  (ZERO_VEC + HASH_VEC)   // 10700
#define INIT_BLK  ((INIT_TOT + 255) / 256)        // 42
#define PACK_BLK  ((NN * WORDS + 255) / 256)      // 2446

// ---------- 1. fused init (replaces memsets) + sign-bit pack ----------
__global__ __launch_bounds__(256) void init_pack_kernel(const float* __restrict__ W,
                                                        char* __restrict__ ws) {
  if (blockIdx.x < INIT_BLK) {
    int t = blockIdx.x * 256 + threadIdx.x;
    if (t < ZERO_VEC) {
      reinterpret_cast<uint4*>(ws)[t] = make_uint4(0u, 0u, 0u, 0u);
    } else if (t < INIT_TOT) {
      reinterpret_cast<uint4*>(ws + WS_HASH)[t - ZERO_VEC] =
          make_uint4(0xFFFFFFFFu, 0xFFFFFFFFu, 0xFFFFFFFFu, 0xFFFFFFFFu);
    }
    return;
  }
  int t = (blockIdx.x - INIT_BLK) * 256 + threadIdx.x;
  if (t >= NN * WORDS) return;
  unsigned int* packed = (unsigned int*)(ws + WS_PACK);
  int w = t / NN;
  int node = t - w * NN;               // consecutive threads -> consecutive nodes, same word
  int d0 = w * 32;
  const float* p = W + (size_t)node * DIM + d0;   // 128B-aligned per-lane chunk
  unsigned int m = 0;
  if (d0 + 32 <= DIM) {
#pragma unroll
    for (int q = 0; q < 8; ++q) {
      float4 v4 = *reinterpret_cast<const float4*>(p + q * 4);
      m |= (__float_as_uint(v4.x) >> 31) << (q * 4);
      m |= (__float_as_uint(v4.y) >> 31) << (q * 4 + 1);
      m |= (__float_as_uint(v4.z) >> 31) << (q * 4 + 2);
      m |= (__float_as_uint(v4.w) >> 31) << (q * 4 + 3);
    }
  } else {
    for (int j = 0; j < DIM - d0; ++j) m |= (__float_as_uint(p[j]) >> 31) << j;
  }
  packed[(size_t)w * NN + node] = m;   // coalesced
}

// DPP wave64 sum: canonical gfx9 sequence; lane 63 ends with the full wave sum.
// Only used for the err gate (~5 orders of magnitude of tolerance at 0.002).
__device__ __forceinline__ float wave_sum_dpp(float x) {
#define DPPADD(ctrl, rm, bm)                                                     \
  {                                                                              \
    int y_ = __builtin_amdgcn_update_dpp(0, __float_as_int(x), ctrl, rm, bm, false); \
    x = __fadd_rn(x, __int_as_float(y_));                                        \
  }
  DPPADD(0x111, 0xF, 0xF);  // row_shr:1
  DPPADD(0x112, 0xF, 0xF);  // row_shr:2
  DPPADD(0x114, 0xF, 0xE);  // row_shr:4
  DPPADD(0x118, 0xF, 0xC);  // row_shr:8
  DPPADD(0x142, 0xA, 0xF);  // row_bcast:15 -> rows 1,3
  DPPADD(0x143, 0xC, 0xF);  // row_bcast:31 -> rows 2,3
#undef DPPADD
  return x;                  // valid in lane 63
}

// ---------- 2. build (count+scan+stable CSR) + pagerank, one block ----------
// CSR construction: atomic fill + per-node insertion sort by edge id == exact
// edge-index order (verified bit-exact since R6). PR gather: register-hoisted
// CSR columns, dummy-padded to REGD (adds of +0.0f after the real terms are
// bit-exact; deg>REGD continues in CSR order in the fallback loop).
__global__ __launch_bounds__(1024) void build_pr_kernel(const int* __restrict__ eidx,
                                                        char* __restrict__ ws) {
  __shared__ unsigned short s_ccol[NE];   // 16 KB  CSR col values
  __shared__ unsigned short s_ced[NE];    // 16 KB  edge ids during build
  __shared__ int s_base[NN + 1];          // 8 KB   CSR row starts
  __shared__ int s_aux[2048];             // degc -> val (f32 alias, in-place)
  __shared__ int s_w[2048];               // rowcnt/scan -> fill counters
  __shared__ float s_wv[2][2048];         // 16 KB  double-buffered val[c]*v[c]
  __shared__ float s_red[2][16];
  float* s_val = (float*)s_aux;

  int tid = threadIdx.x;
  int wid = tid >> 6, lane = tid & 63;

  for (int i = tid; i < 2048; i += 1024) { s_w[i] = 0; s_aux[i] = 0; }
  // zero the dummy tail of both wv buffers once; never written afterwards
  for (int i = NN + tid; i < 2048; i += 1024) { s_wv[0][i] = 0.f; s_wv[1][i] = 0.f; }
  __syncthreads();

  // --- count: row counts (s_w) + col in-degree (s_aux) ---
  int er[8], ec[8];
#pragma unroll
  for (int k = 0; k < 8; ++k) {
    int e = tid + k * 1024;
    er[k] = eidx[e];
    ec[k] = eidx[NE + e];
    atomicAdd(&s_w[er[k]], 1);
    atomicAdd(&s_aux[ec[k]], 1);
  }
  __syncthreads();

  // --- inclusive scan of row counts -> base ---
  {
    int n0 = tid, n1 = tid + 1024;
    for (int st = 1; st < 2048; st <<= 1) {
      int v0 = (n0 >= st) ? s_w[n0 - st] : 0;
      int v1 = (n1 >= st) ? s_w[n1 - st] : 0;
      __syncthreads();
      s_w[n0] += v0;
      s_w[n1] += v1;
      __syncthreads();
    }
    if (tid == 0) s_base[0] = 0;
    for (int n = tid; n < NN; n += 1024) s_base[n + 1] = s_w[n];
  }
  __syncthreads();
  for (int i = tid; i < 2048; i += 1024) s_w[i] = 0;   // reuse as fill counters
  __syncthreads();

  // --- fill (atomic, unordered) keeping edge id ---
#pragma unroll
  for (int k = 0; k < 8; ++k) {
    int e = tid + k * 1024;
    int r = er[k];
    int slot = s_base[r] + atomicAdd(&s_w[r], 1);
    s_ccol[slot] = (unsigned short)ec[k];
    s_ced[slot] = (unsigned short)e;
  }
  __syncthreads();

  // --- per-node insertion sort by edge id (stable CSR) + val + wv[0] init ---
  const float p = 0.0005f;              // f32(1.0/2000)
  const float addv = 0.0005f * 0.15f;   // p * f32(1.0-0.85)
  for (int n = tid; n < NN; n += 1024) {
    int s0 = s_base[n], s1 = s_base[n + 1];
    for (int a = s0 + 1; a < s1; ++a) {
      unsigned short ke = s_ced[a], kc = s_ccol[a];
      int b = a - 1;
      while (b >= s0 && s_ced[b] > ke) {
        s_ced[b + 1] = s_ced[b];
        s_ccol[b + 1] = s_ccol[b];
        --b;
      }
      s_ced[b + 1] = ke;
      s_ccol[b + 1] = kc;
    }
    float vv = 0.85f / (float)s_aux[n];   // inf if deg==0: never gathered
    s_val[n] = vv;                        // in-place alias of s_aux[n]
    s_wv[0][n] = __fmul_rn(vv, p);
  }
  __syncthreads();

  // --- hoist per-thread constants: CSR bounds, val, and register column lists ---
  int b0s = s_base[tid], b0e = s_base[tid + 1];
  int b1s = 0, b1e = 0;
  bool has1 = (tid + 1024 < NN);
  if (has1) { b1s = s_base[tid + 1024]; b1e = s_base[tid + 1025]; }
  float val0 = s_val[tid];
  float val1 = has1 ? s_val[tid + 1024] : 0.f;
  int c0r[REGD], c1r[REGD];
#pragma unroll
  for (int k = 0; k < REGD; ++k) {
    int i0 = b0s + k;
    c0r[k] = (i0 < b0e) ? (int)s_ccol[min(i0, NE - 1)] : DUMMY;
    int i1 = b1s + k;
    c1r[k] = (has1 && i1 < b1e) ? (int)s_ccol[min(i1, NE - 1)] : DUMMY;
  }
  float vc0 = p, vc1 = p;

  float err = __builtin_inff();
  int it = 0;
  int pb = 0;
  while (it < 100 && err >= 0.002f) {
    const float* wv = s_wv[pb];
    float ep = 0.f;
    float sum = 0.f;
#pragma unroll
    for (int k = 0; k < REGD; ++k) sum = __fadd_rn(sum, wv[c0r[k]]);   // +0.0f pads: exact
    for (int k = b0s + REGD; k < b0e; ++k) sum = __fadd_rn(sum, wv[s_ccol[k]]); // rare tail, CSR order
    float vn0 = __fadd_rn(sum, addv);
    ep += fabsf(__fsub_rn(vn0, vc0));
    float vn1 = vc1;
    if (has1) {
      sum = 0.f;
#pragma unroll
      for (int k = 0; k < REGD; ++k) sum = __fadd_rn(sum, wv[c1r[k]]);
      for (int k = b1s + REGD; k < b1e; ++k) sum = __fadd_rn(sum, wv[s_ccol[k]]);
      vn1 = __fadd_rn(sum, addv);
      ep += fabsf(__fsub_rn(vn1, vc1));
    }
    float* wvn = s_wv[pb ^ 1];             // safe: gathers read s_wv[pb]
    wvn[tid] = __fmul_rn(val0, vn0);
    if (has1) wvn[tid + 1024] = __fmul_rn(val1, vn1);
    vc0 = vn0; vc1 = vn1;
    float wsum = wave_sum_dpp(ep);
    if (lane == 63) s_red[pb][wid] = wsum;
    __syncthreads();            // wv[pb^1] + s_red[pb] visible; wv[pb] reads done
    float t = 0.f;
#pragma unroll
    for (int w2 = 0; w2 < 16; ++w2) t += s_red[pb][w2];   // fixed order
    err = t;
    pb ^= 1;
    ++it;
  }
  float* vout = (float*)(ws + WS_V);
  vout[tid] = vc0;
  if (has1) vout[tid + 1024] = vc1;
}

// ---------- 3. stable rank: LDS-staged, 4-way j-split, 32 blocks ----------
__global__ __launch_bounds__(256) void rank_kernel(char* __restrict__ ws) {
  const float* v = (const float*)(ws + WS_V);
  int* rnk = (int*)(ws + WS_RANK);
  __shared__ float s_v[NN];
  __shared__ int s_part[4][RBLK];
  int tid = threadIdx.x;
  for (int j = tid; j < NN; j += 256) s_v[j] = v[j];
  __syncthreads();
  int li = tid & (RBLK - 1);
  int seg = tid >> 6;                    // 0..3
  int i = blockIdx.x * RBLK + li;
  float vi = (i < NN) ? s_v[i] : 0.f;
  const int jper = NN / 4;               // 500
  int j0 = seg * jper, j1 = j0 + jper;
  int r = 0;
  for (int j = j0; j < j1; ++j) {
    float vj = s_v[j];                   // broadcast: conflict-free
    r += ((vj < vi) || (vj == vi && j < i)) ? 1 : 0;
  }
  s_part[seg][li] = r;
  __syncthreads();
  if (tid < RBLK) {
    int i2 = blockIdx.x * RBLK + tid;
    if (i2 < NN)
      rnk[i2] = s_part[0][tid] + s_part[1][tid] + s_part[2][tid] + s_part[3][tid];
  }
}

// ---------- 4. dedup undirected edges via hash set; emit packed ranked pairs ----------
__global__ __launch_bounds__(256) void dedup_kernel(const int* __restrict__ eidx,
                                                    char* __restrict__ ws) {
  int* hash = (int*)(ws + WS_HASH);
  unsigned int* pairs = (unsigned int*)(ws + WS_PAIRS);
  int* Kp = (int*)(ws + WS_K);
  const int* rnk = (const int*)(ws + WS_RANK);
  int e = blockIdx.x * 256 + threadIdx.x;
  int r = eidx[e], c = eidx[NE + e];
  int a = min(r, c), b = max(r, c);
  int key = a * NN + b;
  unsigned int h = ((unsigned int)key * 2654435761u) >> 17;
  for (;;) {
    h &= (HASH_SZ - 1);
    int old = atomicCAS(&hash[h], -1, key);
    if (old == -1) {                       // this edge owns the distinct key
      int idx = atomicAdd(Kp, 1);
      pairs[idx] = ((unsigned int)rnk[a] << 16) | (unsigned int)rnk[b];
      return;
    }
    if (old == key) return;                // duplicate
    ++h;
  }
}

// ---------- 5. per-dim xor-bit counts via ballot+popcount, edge-split grid ----------
__global__ __launch_bounds__(256) void encpop_kernel(char* __restrict__ ws) {
  const unsigned int* packed = (const unsigned int*)(ws + WS_PACK);
  const unsigned int* pairs = (const unsigned int*)(ws + WS_PAIRS);
  const int* Kp = (const int*)(ws + WS_K);
  int* enc_int = (int*)(ws + WS_ENC);
  __shared__ unsigned int s_col[NN];   // this word's bits for all 2000 rows (by rank)
  __shared__ int s_part[4][32];
  int w = blockIdx.x;
  int tid = threadIdx.x;
  int wid = tid >> 6, lane = tid & 63;
  for (int i = tid; i < NN; i += 256) s_col[i] = packed[(size_t)w * NN + i];
  __syncthreads();
  int K = *Kp;
  const int per = NE / ECH;            // 1024
  int e0 = blockIdx.y * per;
  int cnt[32];
#pragma unroll
  for (int b = 0; b < 32; ++b) cnt[b] = 0;
  for (int e = e0 + tid; e < e0 + per; e += 256) {   // uniform trip count: ballot-safe
    unsigned int x = 0;
    if (e < K) {
      unsigned int pk = pairs[e];
      x = s_col[pk >> 16] ^ s_col[pk & 0xffffu];
    }
#pragma unroll
    for (int b = 0; b < 32; ++b)
      cnt[b] += (int)__popcll(__ballot(x & (1u << b)));   // uniform per wave
  }
  if (lane == 0) {
#pragma unroll
    for (int b = 0; b < 32; ++b) s_part[wid][b] = cnt[b];
  }
  __syncthreads();
  if (tid < 32) {
    int tot = s_part[0][tid] + s_part[1][tid] + s_part[2][tid] + s_part[3][tid];
    if (tot) atomicAdd(&enc_int[w * 32 + tid], tot);   // exact integer accumulation
  }
}

// ---------- 6. out[c] = sum_d (K - 2*cnt[d]) * Wc[c][d] ----------
__global__ __launch_bounds__(256) void out_kernel(const float* __restrict__ Wc,
                                                  char* __restrict__ ws,
                                                  float* __restrict__ out) {
  const int* enc_int = (const int*)(ws + WS_ENC);
  int K = *(const int*)(ws + WS_K);
  __shared__ float red[4];
  int c = blockIdx.x;
  float s = 0.f;
  for (int d = threadIdx.x; d < DIM; d += 256)
    s += (float)(K - 2 * enc_int[d]) * Wc[c * DIM + d];
  for (int o = 32; o > 0; o >>= 1) s += __shfl_down(s, o, 64);
  if ((threadIdx.x & 63) == 0) red[threadIdx.x >> 6] = s;
  __syncthreads();
  if (threadIdx.x == 0) out[c] = red[0] + red[1] + red[2] + red[3];
}

extern "C" void kernel_launch(void* const* d_in, const int* in_sizes, int n_in,
                              void* d_out, int out_size, void* d_ws, size_t ws_size,
                              hipStream_t stream) {
  const int* eidx = (const int*)d_in[0];        // edge_index int32 [2, 8192]
  const float* Wn = (const float*)d_in[1];      // node_ids_weight f32 [2000, 10000]
  const float* Wc = (const float*)d_in[2];      // classify_weight f32 [10, 10000]
  float* out = (float*)d_out;
  char* ws = (char*)d_ws;

  init_pack_kernel<<<INIT_BLK + PACK_BLK, 256, 0, stream>>>(Wn, ws);
  build_pr_kernel<<<1, 1024, 0, stream>>>(eidx, ws);
  rank_kernel<<<(NN + RBLK - 1) / RBLK, 256, 0, stream>>>(ws);
  dedup_kernel<<<NE / 256, 256, 0, stream>>>(eidx, ws);
  encpop_kernel<<<dim3(WORDS, ECH), 256, 0, stream>>>(ws);
  out_kernel<<<NCLS, 256, 0, stream>>>(Wc, ws, out);
}

// Round 10
// 87.072 us; speedup vs baseline: 3.0314x; 1.1031x over previous
//
#include <hip/hip_runtime.h>
#include <hip/hip_bf16.h>

#define NN 2000
#define NE 8192
#define DIM 10000
#define NCLS 10
#define HASH_SZ 32768
#define WORDS 313          // ceil(10000/32) packed sign words per node
#define ECH 8              // edge-chunk split for encpop grid.y
#define RBLK 64            // i-rows per rank block
#define REGD 12            // register-hoisted CSR entries per node (fallback loop beyond)
#define DUMMY 2047         // wv[DUMMY] == +0.0f always

// ---- workspace layout (byte offsets) ----
#define WS_K       0                      // int        (distinct-edge counter)
#define WS_ENC     64                     // int[10016] per-dim xor-bit counts
#define WS_V       328576                 // f32[2000]  pagerank result
#define WS_RANK    336576                 // int[2000]  stable rank of each node
#define WS_PAIRS   344576                 // u32[8192]  packed (a<<16)|b node-id pairs per distinct edge
#define WS_HASH    377344                 // int[32768] hash set
#define WS_PACK    508416                 // u32[313*2000] packed sign bits, layout [word][node]

#define ZERO_BYTES 40128                  // [0, 40128): K + ENC counts
#define ZERO_VEC  (ZERO_BYTES / 16)       // 2508 uint4 zero stores
#define HASH_VEC  (HASH_SZ * 4 / 16)      // 8192 uint4 0xFF stores
#define INIT_TOT  (ZERO_VEC + HASH_VEC)   // 10700
#define FUSE_ITEMS (INIT_TOT + NN * WORDS)        // 636700 work items in blocks 1+
#define FUSE_BLK  ((FUSE_ITEMS + 1023) / 1024)    // 622

// DPP wave64 sum: canonical gfx9 sequence; lane 63 ends with the full wave sum.
// Only used for the err gate (~5 orders of magnitude of tolerance at 0.002).
__device__ __forceinline__ float wave_sum_dpp(float x) {
#define DPPADD(ctrl, rm, bm)                                                     \
  {                                                                              \
    int y_ = __builtin_amdgcn_update_dpp(0, __float_as_int(x), ctrl, rm, bm, false); \
    x = __fadd_rn(x, __int_as_float(y_));                                        \
  }
  DPPADD(0x111, 0xF, 0xF);  // row_shr:1
  DPPADD(0x112, 0xF, 0xF);  // row_shr:2
  DPPADD(0x114, 0xF, 0xE);  // row_shr:4
  DPPADD(0x118, 0xF, 0xC);  // row_shr:8
  DPPADD(0x142, 0xA, 0xF);  // row_bcast:15 -> rows 1,3
  DPPADD(0x143, 0xC, 0xF);  // row_bcast:31 -> rows 2,3
#undef DPPADD
  return x;                  // valid in lane 63
}

// ---------- K1: block 0 = build(count+scan+stable CSR)+pagerank (R9-verbatim);
//            blocks 1+ = workspace init + sign-bit pack (runs concurrently) ----------
__global__ __launch_bounds__(1024) void fused_pre_kernel(const int* __restrict__ eidx,
                                                         const float* __restrict__ W,
                                                         char* __restrict__ ws) {
  if (blockIdx.x != 0) {
    // ---- init + pack, 1024 threads/block ----
    int t = (int)(blockIdx.x - 1) * 1024 + threadIdx.x;
    if (t < ZERO_VEC) {
      reinterpret_cast<uint4*>(ws)[t] = make_uint4(0u, 0u, 0u, 0u);
      return;
    }
    if (t < INIT_TOT) {
      reinterpret_cast<uint4*>(ws + WS_HASH)[t - ZERO_VEC] =
          make_uint4(0xFFFFFFFFu, 0xFFFFFFFFu, 0xFFFFFFFFu, 0xFFFFFFFFu);
      return;
    }
    int j = t - INIT_TOT;
    if (j >= NN * WORDS) return;
    unsigned int* packed = (unsigned int*)(ws + WS_PACK);
    int w = j / NN;
    int node = j - w * NN;             // consecutive threads -> consecutive nodes, same word
    int d0 = w * 32;
    const float* p = W + (size_t)node * DIM + d0;   // 128B-aligned per-lane chunk
    unsigned int m = 0;
    if (d0 + 32 <= DIM) {
#pragma unroll
      for (int q = 0; q < 8; ++q) {
        float4 v4 = *reinterpret_cast<const float4*>(p + q * 4);
        m |= (__float_as_uint(v4.x) >> 31) << (q * 4);
        m |= (__float_as_uint(v4.y) >> 31) << (q * 4 + 1);
        m |= (__float_as_uint(v4.z) >> 31) << (q * 4 + 2);
        m |= (__float_as_uint(v4.w) >> 31) << (q * 4 + 3);
      }
    } else {
      for (int q = 0; q < DIM - d0; ++q) m |= (__float_as_uint(p[q]) >> 31) << q;
    }
    packed[(size_t)w * NN + node] = m; // coalesced
    return;
  }

  // ---- block 0: build + pagerank (bit-exact; identical to R9) ----
  __shared__ unsigned short s_ccol[NE];   // 16 KB  CSR col values
  __shared__ unsigned short s_ced[NE];    // 16 KB  edge ids during build
  __shared__ int s_base[NN + 1];          // 8 KB   CSR row starts
  __shared__ int s_aux[2048];             // degc -> val (f32 alias, in-place)
  __shared__ int s_w[2048];               // rowcnt/scan -> fill counters
  __shared__ float s_wv[2][2048];         // 16 KB  double-buffered val[c]*v[c]
  __shared__ float s_red[2][16];
  float* s_val = (float*)s_aux;

  int tid = threadIdx.x;
  int wid = tid >> 6, lane = tid & 63;

  for (int i = tid; i < 2048; i += 1024) { s_w[i] = 0; s_aux[i] = 0; }
  for (int i = NN + tid; i < 2048; i += 1024) { s_wv[0][i] = 0.f; s_wv[1][i] = 0.f; }
  __syncthreads();

  // --- count: row counts (s_w) + col in-degree (s_aux) ---
  int er[8], ec[8];
#pragma unroll
  for (int k = 0; k < 8; ++k) {
    int e = tid + k * 1024;
    er[k] = eidx[e];
    ec[k] = eidx[NE + e];
    atomicAdd(&s_w[er[k]], 1);
    atomicAdd(&s_aux[ec[k]], 1);
  }
  __syncthreads();

  // --- inclusive scan of row counts -> base ---
  {
    int n0 = tid, n1 = tid + 1024;
    for (int st = 1; st < 2048; st <<= 1) {
      int v0 = (n0 >= st) ? s_w[n0 - st] : 0;
      int v1 = (n1 >= st) ? s_w[n1 - st] : 0;
      __syncthreads();
      s_w[n0] += v0;
      s_w[n1] += v1;
      __syncthreads();
    }
    if (tid == 0) s_base[0] = 0;
    for (int n = tid; n < NN; n += 1024) s_base[n + 1] = s_w[n];
  }
  __syncthreads();
  for (int i = tid; i < 2048; i += 1024) s_w[i] = 0;   // reuse as fill counters
  __syncthreads();

  // --- fill (atomic, unordered) keeping edge id ---
#pragma unroll
  for (int k = 0; k < 8; ++k) {
    int e = tid + k * 1024;
    int r = er[k];
    int slot = s_base[r] + atomicAdd(&s_w[r], 1);
    s_ccol[slot] = (unsigned short)ec[k];
    s_ced[slot] = (unsigned short)e;
  }
  __syncthreads();

  // --- per-node insertion sort by edge id (stable CSR) + val + wv[0] init ---
  const float p = 0.0005f;              // f32(1.0/2000)
  const float addv = 0.0005f * 0.15f;   // p * f32(1.0-0.85)
  for (int n = tid; n < NN; n += 1024) {
    int s0 = s_base[n], s1 = s_base[n + 1];
    for (int a = s0 + 1; a < s1; ++a) {
      unsigned short ke = s_ced[a], kc = s_ccol[a];
      int b = a - 1;
      while (b >= s0 && s_ced[b] > ke) {
        s_ced[b + 1] = s_ced[b];
        s_ccol[b + 1] = s_ccol[b];
        --b;
      }
      s_ced[b + 1] = ke;
      s_ccol[b + 1] = kc;
    }
    float vv = 0.85f / (float)s_aux[n];   // inf if deg==0: never gathered
    s_val[n] = vv;                        // in-place alias of s_aux[n]
    s_wv[0][n] = __fmul_rn(vv, p);
  }
  __syncthreads();

  // --- hoist per-thread constants: CSR bounds, val, register column lists ---
  int b0s = s_base[tid], b0e = s_base[tid + 1];
  int b1s = 0, b1e = 0;
  bool has1 = (tid + 1024 < NN);
  if (has1) { b1s = s_base[tid + 1024]; b1e = s_base[tid + 1025]; }
  float val0 = s_val[tid];
  float val1 = has1 ? s_val[tid + 1024] : 0.f;
  int c0r[REGD], c1r[REGD];
#pragma unroll
  for (int k = 0; k < REGD; ++k) {
    int i0 = b0s + k;
    c0r[k] = (i0 < b0e) ? (int)s_ccol[min(i0, NE - 1)] : DUMMY;
    int i1 = b1s + k;
    c1r[k] = (has1 && i1 < b1e) ? (int)s_ccol[min(i1, NE - 1)] : DUMMY;
  }
  float vc0 = p, vc1 = p;

  float err = __builtin_inff();
  int it = 0;
  int pb = 0;
  while (it < 100 && err >= 0.002f) {
    const float* wv = s_wv[pb];
    float ep = 0.f;
    float sum = 0.f;
#pragma unroll
    for (int k = 0; k < REGD; ++k) sum = __fadd_rn(sum, wv[c0r[k]]);   // +0.0f pads: exact
    for (int k = b0s + REGD; k < b0e; ++k) sum = __fadd_rn(sum, wv[s_ccol[k]]); // rare tail, CSR order
    float vn0 = __fadd_rn(sum, addv);
    ep += fabsf(__fsub_rn(vn0, vc0));
    float vn1 = vc1;
    if (has1) {
      sum = 0.f;
#pragma unroll
      for (int k = 0; k < REGD; ++k) sum = __fadd_rn(sum, wv[c1r[k]]);
      for (int k = b1s + REGD; k < b1e; ++k) sum = __fadd_rn(sum, wv[s_ccol[k]]);
      vn1 = __fadd_rn(sum, addv);
      ep += fabsf(__fsub_rn(vn1, vc1));
    }
    float* wvn = s_wv[pb ^ 1];             // safe: gathers read s_wv[pb]
    wvn[tid] = __fmul_rn(val0, vn0);
    if (has1) wvn[tid + 1024] = __fmul_rn(val1, vn1);
    vc0 = vn0; vc1 = vn1;
    float wsum = wave_sum_dpp(ep);
    if (lane == 63) s_red[pb][wid] = wsum;
    __syncthreads();            // wv[pb^1] + s_red[pb] visible; wv[pb] reads done
    float t = 0.f;
#pragma unroll
    for (int w2 = 0; w2 < 16; ++w2) t += s_red[pb][w2];   // fixed order
    err = t;
    pb ^= 1;
    ++it;
  }
  float* vout = (float*)(ws + WS_V);
  vout[tid] = vc0;
  if (has1) vout[tid + 1024] = vc1;
}

// ---------- K2: blocks 0..31 stable rank; blocks 32..63 dedup (independent) ----------
__global__ __launch_bounds__(256) void rank_dedup_kernel(const int* __restrict__ eidx,
                                                         char* __restrict__ ws) {
  int tid = threadIdx.x;
  if (blockIdx.x < 32) {
    // --- stable rank: LDS-staged, 4-way j-split ---
    const float* v = (const float*)(ws + WS_V);
    int* rnk = (int*)(ws + WS_RANK);
    __shared__ float s_v[NN];
    __shared__ int s_part[4][RBLK];
    for (int j = tid; j < NN; j += 256) s_v[j] = v[j];
    __syncthreads();
    int li = tid & (RBLK - 1);
    int seg = tid >> 6;                  // 0..3
    int i = blockIdx.x * RBLK + li;
    float vi = (i < NN) ? s_v[i] : 0.f;
    const int jper = NN / 4;             // 500
    int j0 = seg * jper, j1 = j0 + jper;
    int r = 0;
    for (int j = j0; j < j1; ++j) {
      float vj = s_v[j];                 // broadcast: conflict-free
      r += ((vj < vi) || (vj == vi && j < i)) ? 1 : 0;
    }
    s_part[seg][li] = r;
    __syncthreads();
    if (tid < RBLK) {
      int i2 = blockIdx.x * RBLK + tid;
      if (i2 < NN)
        rnk[i2] = s_part[0][tid] + s_part[1][tid] + s_part[2][tid] + s_part[3][tid];
    }
  } else {
    // --- dedup via hash set; pairs carry NODE IDS (rank translation in encpop) ---
    int* hash = (int*)(ws + WS_HASH);
    unsigned int* pairs = (unsigned int*)(ws + WS_PAIRS);
    int* Kp = (int*)(ws + WS_K);
    int e = (int)(blockIdx.x - 32) * 256 + tid;
    int r = eidx[e], c = eidx[NE + e];
    int a = min(r, c), b = max(r, c);
    int key = a * NN + b;
    unsigned int h = ((unsigned int)key * 2654435761u) >> 17;
    for (;;) {
      h &= (HASH_SZ - 1);
      int old = atomicCAS(&hash[h], -1, key);
      if (old == -1) {                   // this edge owns the distinct key
        int idx = atomicAdd(Kp, 1);
        pairs[idx] = ((unsigned int)a << 16) | (unsigned int)b;
        return;
      }
      if (old == key) return;            // duplicate
      ++h;
    }
  }
}

// ---------- K3: per-dim xor-bit counts; node->rank translation at staging ----------
__global__ __launch_bounds__(256) void encpop_kernel(char* __restrict__ ws) {
  const unsigned int* packed = (const unsigned int*)(ws + WS_PACK);
  const unsigned int* pairs = (const unsigned int*)(ws + WS_PAIRS);
  const int* Kp = (const int*)(ws + WS_K);
  const int* rnk_g = (const int*)(ws + WS_RANK);
  int* enc_int = (int*)(ws + WS_ENC);
  __shared__ unsigned short s_rnk[NN]; // node -> rank
  __shared__ unsigned int s_col[NN];   // node -> this word's bits of W-row rank[node]
  __shared__ int s_part[4][32];
  int w = blockIdx.x;
  int tid = threadIdx.x;
  int wid = tid >> 6, lane = tid & 63;
  for (int i = tid; i < NN; i += 256) s_rnk[i] = (unsigned short)rnk_g[i];
  __syncthreads();
  for (int i = tid; i < NN; i += 256)
    s_col[i] = packed[(size_t)w * NN + s_rnk[i]];   // L2-resident gather
  __syncthreads();
  int K = *Kp;
  const int per = NE / ECH;            // 1024
  int e0 = blockIdx.y * per;
  int cnt[32];
#pragma unroll
  for (int b = 0; b < 32; ++b) cnt[b] = 0;
  for (int e = e0 + tid; e < e0 + per; e += 256) {   // uniform trip count: ballot-safe
    unsigned int x = 0;
    if (e < K) {
      unsigned int pk = pairs[e];
      x = s_col[pk >> 16] ^ s_col[pk & 0xffffu];
    }
#pragma unroll
    for (int b = 0; b < 32; ++b)
      cnt[b] += (int)__popcll(__ballot(x & (1u << b)));   // uniform per wave
  }
  if (lane == 0) {
#pragma unroll
    for (int b = 0; b < 32; ++b) s_part[wid][b] = cnt[b];
  }
  __syncthreads();
  if (tid < 32) {
    int tot = s_part[0][tid] + s_part[1][tid] + s_part[2][tid] + s_part[3][tid];
    if (tot) atomicAdd(&enc_int[w * 32 + tid], tot);   // exact integer accumulation
  }
}

// ---------- K4: out[c] = sum_d (K - 2*cnt[d]) * Wc[c][d] ----------
__global__ __launch_bounds__(256) void out_kernel(const float* __restrict__ Wc,
                                                  char* __restrict__ ws,
                                                  float* __restrict__ out) {
  const int* enc_int = (const int*)(ws + WS_ENC);
  int K = *(const int*)(ws + WS_K);
  __shared__ float red[4];
  int c = blockIdx.x;
  float s = 0.f;
  for (int d = threadIdx.x; d < DIM; d += 256)
    s += (float)(K - 2 * enc_int[d]) * Wc[c * DIM + d];
  for (int o = 32; o > 0; o >>= 1) s += __shfl_down(s, o, 64);
  if ((threadIdx.x & 63) == 0) red[threadIdx.x >> 6] = s;
  __syncthreads();
  if (threadIdx.x == 0) out[c] = red[0] + red[1] + red[2] + red[3];
}

extern "C" void kernel_launch(void* const* d_in, const int* in_sizes, int n_in,
                              void* d_out, int out_size, void* d_ws, size_t ws_size,
                              hipStream_t stream) {
  const int* eidx = (const int*)d_in[0];        // edge_index int32 [2, 8192]
  const float* Wn = (const float*)d_in[1];      // node_ids_weight f32 [2000, 10000]
  const float* Wc = (const float*)d_in[2];      // classify_weight f32 [10, 10000]
  float* out = (float*)d_out;
  char* ws = (char*)d_ws;

  fused_pre_kernel<<<FUSE_BLK + 1, 1024, 0, stream>>>(eidx, Wn, ws);
  rank_dedup_kernel<<<64, 256, 0, stream>>>(eidx, ws);
  encpop_kernel<<<dim3(WORDS, ECH), 256, 0, stream>>>(ws);
  out_kernel<<<NCLS, 256, 0, stream>>>(Wc, ws, out);
}